// Round 1
// baseline (219.416 us; speedup 1.0000x reference)
//
#include <hip/hip_runtime.h>
#include <hip/hip_bf16.h>

typedef __attribute__((ext_vector_type(8))) short s16x8;
typedef __attribute__((ext_vector_type(4))) float f32x4;

#define K_DIM 1024
#define I_DIM 4096

__device__ __forceinline__ unsigned short f2bf_bits(float v) {
    // exact for integers |v| <= 255 (<= 8 significand bits -> low 16 mantissa bits zero)
    return (unsigned short)(__builtin_bit_cast(unsigned int, v) >> 16);
}

__device__ __forceinline__ float fakeq_int(float x, float s, float zp) {
    // returns round(x/s) + zp clipped to [0,255], minus zp  (exact small integer)
    float q = fminf(fmaxf(rintf(x / s) + zp, 0.0f), 255.0f);
    return q - zp;
}

// ---- quantize activations: fp32 [M*K] -> bf16 integer codes [Mpad*K] (pad rows = 0)
__global__ void quant_x_kernel(const float* __restrict__ x, unsigned short* __restrict__ Aq,
                               const float* __restrict__ a_scale, const float* __restrict__ a_zero,
                               long long n_src, long long n_dst) {
    long long i = ((long long)blockIdx.x * blockDim.x + threadIdx.x) * 4;
    if (i >= n_dst) return;
    ushort4 o;
    if (i < n_src) {
        float s = a_scale[0];
        float zp = rintf(a_zero[0]);
        float4 v = *(const float4*)(x + i);
        o.x = f2bf_bits(fakeq_int(v.x, s, zp));
        o.y = f2bf_bits(fakeq_int(v.y, s, zp));
        o.z = f2bf_bits(fakeq_int(v.z, s, zp));
        o.w = f2bf_bits(fakeq_int(v.w, s, zp));
    } else {
        o.x = o.y = o.z = o.w = 0;
    }
    *(ushort4*)(Aq + i) = o;
}

// ---- quantize weights: fp32 [I*K] -> bf16 integer codes, per-row scale/zero
__global__ void quant_w_kernel(const float* __restrict__ w, unsigned short* __restrict__ Wq,
                               const float* __restrict__ w_scale, const float* __restrict__ w_zero,
                               long long n) {
    long long i = ((long long)blockIdx.x * blockDim.x + threadIdx.x) * 4;
    if (i >= n) return;
    long long row = i >> 10;  // K = 1024
    float s = w_scale[row];
    float zp = rintf(w_zero[row]);
    float4 v = *(const float4*)(w + i);
    ushort4 o;
    o.x = f2bf_bits(fakeq_int(v.x, s, zp));
    o.y = f2bf_bits(fakeq_int(v.y, s, zp));
    o.z = f2bf_bits(fakeq_int(v.z, s, zp));
    o.w = f2bf_bits(fakeq_int(v.w, s, zp));
    *(ushort4*)(Wq + i) = o;
}

// ---- GEMM 128x128 tile, BK=32, 4 waves (2x2 of 64x64), 16x16x32 bf16 MFMA,
//      global_load_lds width=16 staging (m97 structure), fused scale+bias+exact GELU.
__global__ __launch_bounds__(256) void gemm_gelu_kernel(
    const unsigned short* __restrict__ Aq,   // [Mpad][K] bf16 bits
    const unsigned short* __restrict__ Wq,   // [I][K]    bf16 bits
    const float* __restrict__ bias,
    const float* __restrict__ w_scale,
    const float* __restrict__ a_scale,
    float* __restrict__ out,                 // [M][I] fp32
    int M, int Ntiles) {
    __shared__ alignas(16) unsigned short As[128 * 32];
    __shared__ alignas(16) unsigned short Bs[128 * 32];

    // bijective XCD-aware swizzle (8 XCDs)
    int nwg = gridDim.x;
    int bid = blockIdx.x;
    int xcd = bid & 7, lin = bid >> 3;
    int q = nwg >> 3, r = nwg & 7;
    int swz = (xcd < r ? xcd * (q + 1) : r * (q + 1) + (xcd - r) * q) + lin;
    int mt = swz / Ntiles, nt = swz % Ntiles;

    int tid = threadIdx.x;
    int wave = tid >> 6, lane = tid & 63;
    int wr = wave >> 1, wc = wave & 1;

    long long mrow0 = (long long)mt * 128;
    int ncol0 = nt * 128;

    f32x4 acc[4][4];
#pragma unroll
    for (int m = 0; m < 4; ++m)
#pragma unroll
        for (int n = 0; n < 4; ++n) acc[m][n] = (f32x4)0.0f;

    // staging addresses: flat element f = issue*2048 + tid*8 over a 128x32 tile
    int f0 = tid * 8;
    int fr0 = f0 >> 5;          // row within tile (issue 0); issue 1 adds 64 rows
    int fk0 = f0 & 31;
    const unsigned short* gA0 = Aq + (mrow0 + fr0) * K_DIM + fk0;
    const unsigned short* gA1 = gA0 + 64LL * K_DIM;
    const unsigned short* gB0 = Wq + ((long long)ncol0 + fr0) * K_DIM + fk0;
    const unsigned short* gB1 = gB0 + 64LL * K_DIM;
    unsigned short* lA0 = &As[wave * 512];
    unsigned short* lA1 = &As[2048 + wave * 512];
    unsigned short* lB0 = &Bs[wave * 512];
    unsigned short* lB1 = &Bs[2048 + wave * 512];

    // LDS->fragment read addressing (A: row = l&15, k = (l>>4)*8 .. +8; B identical, K-major)
    int arow = wr * 64 + (lane & 15);
    int brow = wc * 64 + (lane & 15);
    int koff = (lane >> 4) * 8;

    for (int k0 = 0; k0 < K_DIM; k0 += 32) {
        __builtin_amdgcn_global_load_lds((const __attribute__((address_space(1))) void*)(gA0 + k0),
                                         (__attribute__((address_space(3))) void*)lA0, 16, 0, 0);
        __builtin_amdgcn_global_load_lds((const __attribute__((address_space(1))) void*)(gA1 + k0),
                                         (__attribute__((address_space(3))) void*)lA1, 16, 0, 0);
        __builtin_amdgcn_global_load_lds((const __attribute__((address_space(1))) void*)(gB0 + k0),
                                         (__attribute__((address_space(3))) void*)lB0, 16, 0, 0);
        __builtin_amdgcn_global_load_lds((const __attribute__((address_space(1))) void*)(gB1 + k0),
                                         (__attribute__((address_space(3))) void*)lB1, 16, 0, 0);
        __syncthreads();  // drains vmcnt(0) before any wave reads LDS

        s16x8 a[4], b[4];
#pragma unroll
        for (int m = 0; m < 4; ++m) a[m] = *(const s16x8*)&As[(arow + m * 16) * 32 + koff];
#pragma unroll
        for (int n = 0; n < 4; ++n) b[n] = *(const s16x8*)&Bs[(brow + n * 16) * 32 + koff];

#pragma unroll
        for (int m = 0; m < 4; ++m)
#pragma unroll
            for (int n = 0; n < 4; ++n)
                acc[m][n] = __builtin_amdgcn_mfma_f32_16x16x32_bf16(a[m], b[n], acc[m][n], 0, 0, 0);
        __syncthreads();
    }

    // epilogue: y = a_scale*w_scale[col]*acc + bias[col]; exact GELU
    float asc = a_scale[0];
    long long row0 = mrow0 + wr * 64;
    int colb = ncol0 + wc * 64 + (lane & 15);
    int rsub = (lane >> 4) * 4;
#pragma unroll
    for (int n = 0; n < 4; ++n) {
        int col = colb + n * 16;
        float sc = asc * w_scale[col];
        float bz = bias[col];
#pragma unroll
        for (int m = 0; m < 4; ++m) {
            long long rb = row0 + m * 16 + rsub;
#pragma unroll
            for (int rg = 0; rg < 4; ++rg) {
                long long rowi = rb + rg;
                if (rowi < M) {
                    float y = acc[m][n][rg] * sc + bz;
                    float g = 0.5f * y * (1.0f + erff(y * 0.70710678118654752f));
                    out[rowi * I_DIM + col] = g;
                }
            }
        }
    }
}

// ---- safety-net fallback (only if workspace is too small): naive on-the-fly
__global__ void fallback_kernel(const float* __restrict__ x, const float* __restrict__ w,
                                const float* __restrict__ bias, const float* __restrict__ w_scale,
                                const float* __restrict__ w_zero, const float* __restrict__ a_scale,
                                const float* __restrict__ a_zero, float* __restrict__ out,
                                long long M) {
    long long gid = (long long)blockIdx.x * blockDim.x + threadIdx.x;
    if (gid >= M * I_DIM) return;
    int i = (int)(gid & (I_DIM - 1));
    long long row = gid >> 12;
    float as = a_scale[0], az = rintf(a_zero[0]);
    float wsc = w_scale[i], wz = rintf(w_zero[i]);
    const float* xr = x + row * K_DIM;
    const float* wrp = w + (long long)i * K_DIM;
    float accf = 0.0f;
    for (int k = 0; k < K_DIM; ++k) {
        float xq = fakeq_int(xr[k], as, az);
        float wq = fakeq_int(wrp[k], wsc, wz);
        accf += xq * wq;
    }
    float y = accf * as * wsc + bias[i];
    out[gid] = 0.5f * y * (1.0f + erff(y * 0.70710678118654752f));
}

extern "C" void kernel_launch(void* const* d_in, const int* in_sizes, int n_in,
                              void* d_out, int out_size, void* d_ws, size_t ws_size,
                              hipStream_t stream) {
    const float* x       = (const float*)d_in[0];
    const float* w       = (const float*)d_in[1];
    const float* bias    = (const float*)d_in[2];
    const float* w_scale = (const float*)d_in[3];
    const float* w_zero  = (const float*)d_in[4];
    const float* a_scale = (const float*)d_in[5];
    const float* a_zero  = (const float*)d_in[6];
    float* out = (float*)d_out;

    long long n_x = in_sizes[0];            // M*K
    long long M = n_x / K_DIM;              // 12608
    long long Mpad = ((M + 127) / 128) * 128;
    size_t needA = (size_t)Mpad * K_DIM * 2;
    size_t needW = (size_t)I_DIM * K_DIM * 2;

    if (ws_size >= needA + needW) {
        unsigned short* Aq = (unsigned short*)d_ws;
        unsigned short* Wq = (unsigned short*)((char*)d_ws + needA);

        long long ndx = Mpad * K_DIM;
        long long blocksX = (ndx / 4 + 255) / 256;
        quant_x_kernel<<<(int)blocksX, 256, 0, stream>>>(x, Aq, a_scale, a_zero, n_x, ndx);

        long long ndw = (long long)I_DIM * K_DIM;
        long long blocksW = (ndw / 4 + 255) / 256;
        quant_w_kernel<<<(int)blocksW, 256, 0, stream>>>(w, Wq, w_scale, w_zero, ndw);

        int Mtiles = (int)(Mpad / 128);
        int Ntiles = I_DIM / 128;
        gemm_gelu_kernel<<<Mtiles * Ntiles, 256, 0, stream>>>(Aq, Wq, bias, w_scale, a_scale,
                                                              out, (int)M, Ntiles);
    } else {
        long long total = M * I_DIM;
        long long blocks = (total + 255) / 256;
        fallback_kernel<<<(int)blocks, 256, 0, stream>>>(x, w, bias, w_scale, w_zero,
                                                         a_scale, a_zero, out, M);
    }
}